// Round 7
// baseline (501.218 us; speedup 1.0000x reference)
//
#include <hip/hip_runtime.h>

#define Bsz 4096
#define Tlen 512
#define IND 18
#define HD 12

__device__ __forceinline__ float sigmoid_f(float x) {
  return __builtin_amdgcn_rcpf(1.0f + __expf(-x));
}
__device__ __forceinline__ float tanh_f(float x) {
  // tanh(x) = 1 - 2/(1+exp(2x)); saturates correctly at +-inf
  return 1.0f - 2.0f * __builtin_amdgcn_rcpf(1.0f + __expf(2.0f * x));
}

// ds_swizzle BitMode: src_lane = ((lane & AND) | OR) ^ XOR (per 32-lane half).
// bcast16<K>: AND=0x10 keeps the 16-group bit, OR=K -> every lane of a
// 16-lane group reads element K of that group. Pure lane interchange, no LDS
// storage, no barrier.
template <int K>
__device__ __forceinline__ float bcast16(float x) {
  return __uint_as_float((unsigned)__builtin_amdgcn_ds_swizzle(
      (int)__float_as_uint(x), (K << 5) | 0x10));
}
// xor-butterfly term (direction-free reduction within 16-lane group)
template <int X>
__device__ __forceinline__ float swzxor(float x) {
  return __uint_as_float((unsigned)__builtin_amdgcn_ds_swizzle(
      (int)__float_as_uint(x), (X << 10) | 0x1F));
}

// acc trio += W[:,k] * h_k for k = 0..11, h broadcast from lane k in-register.
#define MV3(h, W0, W1, W2, a0, a1, a2)                                                   \
  do {                                                                                   \
    float hb_;                                                                           \
    hb_ = bcast16<0>(h);  a0 = fmaf(hb_, W0[0],  a0); a1 = fmaf(hb_, W1[0],  a1); a2 = fmaf(hb_, W2[0],  a2); \
    hb_ = bcast16<1>(h);  a0 = fmaf(hb_, W0[1],  a0); a1 = fmaf(hb_, W1[1],  a1); a2 = fmaf(hb_, W2[1],  a2); \
    hb_ = bcast16<2>(h);  a0 = fmaf(hb_, W0[2],  a0); a1 = fmaf(hb_, W1[2],  a1); a2 = fmaf(hb_, W2[2],  a2); \
    hb_ = bcast16<3>(h);  a0 = fmaf(hb_, W0[3],  a0); a1 = fmaf(hb_, W1[3],  a1); a2 = fmaf(hb_, W2[3],  a2); \
    hb_ = bcast16<4>(h);  a0 = fmaf(hb_, W0[4],  a0); a1 = fmaf(hb_, W1[4],  a1); a2 = fmaf(hb_, W2[4],  a2); \
    hb_ = bcast16<5>(h);  a0 = fmaf(hb_, W0[5],  a0); a1 = fmaf(hb_, W1[5],  a1); a2 = fmaf(hb_, W2[5],  a2); \
    hb_ = bcast16<6>(h);  a0 = fmaf(hb_, W0[6],  a0); a1 = fmaf(hb_, W1[6],  a1); a2 = fmaf(hb_, W2[6],  a2); \
    hb_ = bcast16<7>(h);  a0 = fmaf(hb_, W0[7],  a0); a1 = fmaf(hb_, W1[7],  a1); a2 = fmaf(hb_, W2[7],  a2); \
    hb_ = bcast16<8>(h);  a0 = fmaf(hb_, W0[8],  a0); a1 = fmaf(hb_, W1[8],  a1); a2 = fmaf(hb_, W2[8],  a2); \
    hb_ = bcast16<9>(h);  a0 = fmaf(hb_, W0[9],  a0); a1 = fmaf(hb_, W1[9],  a1); a2 = fmaf(hb_, W2[9],  a2); \
    hb_ = bcast16<10>(h); a0 = fmaf(hb_, W0[10], a0); a1 = fmaf(hb_, W1[10], a1); a2 = fmaf(hb_, W2[10], a2); \
    hb_ = bcast16<11>(h); a0 = fmaf(hb_, W0[11], a0); a1 = fmaf(hb_, W1[11], a1); a2 = fmaf(hb_, W2[11], a2); \
  } while (0)

// One 16-lane group per batch, whole network per wave: h1/h2 lane-resident,
// matvecs via in-register broadcast (ds_swizzle), FC via xor-butterfly.
// NO shared memory, NO barriers, no inter-wave coupling. 256 blocks * 4
// waves = 1024 waves = 1 wave/SIMD; per-step issue ~530 cyc >> critical
// path ~260 cyc -> issue-bound.
extern "C" __global__ void __launch_bounds__(256, 1) gru2_swz(
    const float* __restrict__ x,
    const float* __restrict__ wih0, const float* __restrict__ whh0,
    const float* __restrict__ bih0, const float* __restrict__ bhh0,
    const float* __restrict__ wih1, const float* __restrict__ whh1,
    const float* __restrict__ bih1, const float* __restrict__ bhh1,
    const float* __restrict__ fcw, const float* __restrict__ fcb,
    float* __restrict__ out)
{
  const int tid    = threadIdx.x;
  const int lane15 = tid & 15;
  const int g      = tid >> 4;            // group in block (0..15)
  const int b      = blockIdx.x * 16 + g;
  const int j      = (lane15 < HD) ? lane15 : (HD - 1);   // clamped row

  // ---- weights (registers; lanes 12-15 hold clamped copies, never broadcast) ----
  float wr[IND], wz[IND], wn[IND];
#pragma unroll
  for (int k = 0; k < IND; ++k) {
    wr[k] = wih0[(0 * HD + j) * IND + k];
    wz[k] = wih0[(1 * HD + j) * IND + k];
    wn[k] = wih0[(2 * HD + j) * IND + k];
  }
  float u0r[HD], u0z[HD], u0n[HD];   // layer0 hh
  float v1r[HD], v1z[HD], v1n[HD];   // layer1 ih
  float u1r[HD], u1z[HD], u1n[HD];   // layer1 hh
#pragma unroll
  for (int k = 0; k < HD; ++k) {
    u0r[k] = whh0[(0 * HD + j) * HD + k];
    u0z[k] = whh0[(1 * HD + j) * HD + k];
    u0n[k] = whh0[(2 * HD + j) * HD + k];
    v1r[k] = wih1[(0 * HD + j) * HD + k];
    v1z[k] = wih1[(1 * HD + j) * HD + k];
    v1n[k] = wih1[(2 * HD + j) * HD + k];
    u1r[k] = whh1[(0 * HD + j) * HD + k];
    u1z[k] = whh1[(1 * HD + j) * HD + k];
    u1n[k] = whh1[(2 * HD + j) * HD + k];
  }
  const float fwl = (lane15 < HD) ? fcw[lane15] : 0.f;   // lane's FC weight
  const float br0 = bih0[j] + bhh0[j];
  const float bz0 = bih0[HD + j] + bhh0[HD + j];
  const float bi0 = bih0[2 * HD + j];
  const float bh0 = bhh0[2 * HD + j];
  const float br1 = bih1[j] + bhh1[j];
  const float bz1 = bih1[HD + j] + bhh1[HD + j];
  const float bi1 = bih1[2 * HD + j];
  const float bh1 = bhh1[2 * HD + j];
  const float fb  = fcb[0];

  float h1 = 0.f, h2 = 0.f;
  const float2* xp2 = (const float2*)(x + (size_t)b * Tlen * IND);
  float* outp = out + (size_t)b * Tlen;

  float2 xA[9], xB[9];
#pragma unroll
  for (int i = 0; i < 9; ++i) xA[i] = xp2[i];       // x[0]
#pragma unroll
  for (int i = 0; i < 9; ++i) xB[i] = xp2[9 + i];   // x[1]

#define STEP(XB, TT, TN)                                                                 \
  do {                                                                                   \
    /* layer 0: gi0 full dots in-lane + hh0 via broadcast */                             \
    float ar = br0, az = bz0, an = bi0, hn = bh0;                                        \
    _Pragma("unroll")                                                                    \
    for (int i = 0; i < 9; ++i) {                                                        \
      ar = fmaf(XB[i].x, wr[2 * i], ar); ar = fmaf(XB[i].y, wr[2 * i + 1], ar);          \
      az = fmaf(XB[i].x, wz[2 * i], az); az = fmaf(XB[i].y, wz[2 * i + 1], az);          \
      an = fmaf(XB[i].x, wn[2 * i], an); an = fmaf(XB[i].y, wn[2 * i + 1], an);          \
    }                                                                                    \
    MV3(h1, u0r, u0z, u0n, ar, az, hn);                                                  \
    float r = sigmoid_f(ar), zg = sigmoid_f(az);                                         \
    float n = tanh_f(an + r * hn);                                                       \
    h1 = n + zg * (h1 - n);                                                              \
    /* layer 1: hh1 (old h2, independent -> fills gate latency) + ih1 (new h1) */        \
    float a1r = br1, a1z = bz1, a1n = bi1, h1n = bh1;                                    \
    MV3(h2, u1r, u1z, u1n, a1r, a1z, h1n);                                               \
    MV3(h1, v1r, v1z, v1n, a1r, a1z, a1n);                                               \
    float r1 = sigmoid_f(a1r), z1 = sigmoid_f(a1z);                                      \
    float n1 = tanh_f(a1n + r1 * h1n);                                                   \
    h2 = n1 + z1 * (h2 - n1);                                                            \
    /* FC: xor-butterfly over the 16-lane group (lanes >=12 contribute 0) */             \
    float p = h2 * fwl;                                                                  \
    p += swzxor<1>(p); p += swzxor<2>(p); p += swzxor<4>(p); p += swzxor<8>(p);          \
    if (lane15 == 0) outp[TT] = p + fb;                                                  \
    /* prefetch x[TN] into this buffer (consumed 2 steps from now) */                    \
    if ((TN) < Tlen) {                                                                   \
      const float2* q_ = xp2 + (size_t)(TN) * 9;                                         \
      _Pragma("unroll")                                                                  \
      for (int i = 0; i < 9; ++i) XB[i] = q_[i];                                         \
    }                                                                                    \
  } while (0)

  for (int t = 0; t < Tlen; t += 2) {
    STEP(xA, t, t + 2);
    STEP(xB, t + 1, t + 3);
  }
#undef STEP
}

extern "C" void kernel_launch(void* const* d_in, const int* in_sizes, int n_in,
                              void* d_out, int out_size, void* d_ws, size_t ws_size,
                              hipStream_t stream) {
  (void)in_sizes; (void)n_in; (void)d_ws; (void)ws_size; (void)out_size;
  const float* x    = (const float*)d_in[0];
  const float* wih0 = (const float*)d_in[1];
  const float* whh0 = (const float*)d_in[2];
  const float* bih0 = (const float*)d_in[3];
  const float* bhh0 = (const float*)d_in[4];
  const float* wih1 = (const float*)d_in[5];
  const float* whh1 = (const float*)d_in[6];
  const float* bih1 = (const float*)d_in[7];
  const float* bhh1 = (const float*)d_in[8];
  const float* fcw  = (const float*)d_in[9];
  const float* fcb  = (const float*)d_in[10];
  float* out = (float*)d_out;

  hipLaunchKernelGGL(gru2_swz, dim3(Bsz / 16), dim3(256), 0, stream,
                     x, wih0, whh0, bih0, bhh0, wih1, whh1, bih1, bhh1, fcw, fcb, out);
}

// Round 8
// 401.014 us; speedup vs baseline: 1.2499x; 1.2499x over previous
//
#include <hip/hip_runtime.h>

#define Bsz 4096
#define Tlen 512
#define IND 18
#define HD 12

__device__ __forceinline__ float sigmoid_f(float x) {
  return __builtin_amdgcn_rcpf(1.0f + __expf(-x));
}
__device__ __forceinline__ float tanh_f(float x) {
  // tanh(x) = 1 - 2/(1+exp(2x)); saturates correctly at +-inf
  return 1.0f - 2.0f * __builtin_amdgcn_rcpf(1.0f + __expf(2.0f * x));
}

// DPP row_ror:i — VALU-rate lane rotation within each 16-lane row.
// No LDS pipe, no lgkmcnt, no barrier. All rotations read the ORIGINAL h
// (no serial chain). The source-lane mapping src(j,i) is probed at runtime
// (mov_dpp of the lane index), so weight reindexing is convention-agnostic.
#define ROTI(v, i) __builtin_amdgcn_mov_dpp((v), 0x120 | (i), 0xF, 0xF, true)
#define ROTF(h, i) __uint_as_float((unsigned)ROTI((int)__float_as_uint(h), (i)))

#define MV3(h, W0, W1, W2, a0, a1, a2, i)                                   \
  { float hb_ = ROTF(h, i);                                                 \
    a0 = fmaf(hb_, W0[i], a0); a1 = fmaf(hb_, W1[i], a1);                   \
    a2 = fmaf(hb_, W2[i], a2); }

#define MV4(h, W0, W1, W2, W3, a0, a1, a2, a3, i)                           \
  { float hb_ = ROTF(h, i);                                                 \
    a0 = fmaf(hb_, W0[i], a0); a1 = fmaf(hb_, W1[i], a1);                   \
    a2 = fmaf(hb_, W2[i], a2); a3 = fmaf(hb_, W3[i], a3); }

#define MV3_ALL(h, W0, W1, W2, a0, a1, a2)                                  \
  do {                                                                      \
    a0 = fmaf(h, W0[0], a0); a1 = fmaf(h, W1[0], a1); a2 = fmaf(h, W2[0], a2); \
    MV3(h, W0, W1, W2, a0, a1, a2, 1)  MV3(h, W0, W1, W2, a0, a1, a2, 2)    \
    MV3(h, W0, W1, W2, a0, a1, a2, 3)  MV3(h, W0, W1, W2, a0, a1, a2, 4)    \
    MV3(h, W0, W1, W2, a0, a1, a2, 5)  MV3(h, W0, W1, W2, a0, a1, a2, 6)    \
    MV3(h, W0, W1, W2, a0, a1, a2, 7)  MV3(h, W0, W1, W2, a0, a1, a2, 8)    \
    MV3(h, W0, W1, W2, a0, a1, a2, 9)  MV3(h, W0, W1, W2, a0, a1, a2, 10)   \
    MV3(h, W0, W1, W2, a0, a1, a2, 11) MV3(h, W0, W1, W2, a0, a1, a2, 12)   \
    MV3(h, W0, W1, W2, a0, a1, a2, 13) MV3(h, W0, W1, W2, a0, a1, a2, 14)   \
    MV3(h, W0, W1, W2, a0, a1, a2, 15)                                      \
  } while (0)

#define MV4_ALL(h, W0, W1, W2, W3, a0, a1, a2, a3)                          \
  do {                                                                      \
    a0 = fmaf(h, W0[0], a0); a1 = fmaf(h, W1[0], a1);                       \
    a2 = fmaf(h, W2[0], a2); a3 = fmaf(h, W3[0], a3);                       \
    MV4(h, W0, W1, W2, W3, a0, a1, a2, a3, 1)                               \
    MV4(h, W0, W1, W2, W3, a0, a1, a2, a3, 2)                               \
    MV4(h, W0, W1, W2, W3, a0, a1, a2, a3, 3)                               \
    MV4(h, W0, W1, W2, W3, a0, a1, a2, a3, 4)                               \
    MV4(h, W0, W1, W2, W3, a0, a1, a2, a3, 5)                               \
    MV4(h, W0, W1, W2, W3, a0, a1, a2, a3, 6)                               \
    MV4(h, W0, W1, W2, W3, a0, a1, a2, a3, 7)                               \
    MV4(h, W0, W1, W2, W3, a0, a1, a2, a3, 8)                               \
    MV4(h, W0, W1, W2, W3, a0, a1, a2, a3, 9)                               \
    MV4(h, W0, W1, W2, W3, a0, a1, a2, a3, 10)                              \
    MV4(h, W0, W1, W2, W3, a0, a1, a2, a3, 11)                              \
    MV4(h, W0, W1, W2, W3, a0, a1, a2, a3, 12)                              \
    MV4(h, W0, W1, W2, W3, a0, a1, a2, a3, 13)                              \
    MV4(h, W0, W1, W2, W3, a0, a1, a2, a3, 14)                              \
    MV4(h, W0, W1, W2, W3, a0, a1, a2, a3, 15)                              \
  } while (0)

// One 16-lane group per batch (12 active rows), whole network per group.
// h1/h2 lane-resident; all matvecs via DPP rotate-and-FMA with per-lane
// reindexed (and zero-padded) weights. NO LDS, NO barriers, independent
// waves. 256 blocks x 4 waves = 1024 waves = 1 wave/SIMD, issue-bound.
extern "C" __global__ void __launch_bounds__(256, 1) gru2_dpp(
    const float* __restrict__ x,
    const float* __restrict__ wih0, const float* __restrict__ whh0,
    const float* __restrict__ bih0, const float* __restrict__ bhh0,
    const float* __restrict__ wih1, const float* __restrict__ whh1,
    const float* __restrict__ bih1, const float* __restrict__ bhh1,
    const float* __restrict__ fcw, const float* __restrict__ fcb,
    float* __restrict__ out)
{
  const int tid    = threadIdx.x;
  const int lane15 = tid & 15;
  const int g      = tid >> 4;           // group in block (0..15)
  const int b      = blockIdx.x * 16 + g;
  const int j      = (lane15 < HD) ? lane15 : (HD - 1);

  // ---- probe the HW rotation mapping: src(j,i) for each rotate amount ----
  int srcl[16];
  srcl[0]  = lane15;
  srcl[1]  = ROTI(lane15, 1);   srcl[2]  = ROTI(lane15, 2);
  srcl[3]  = ROTI(lane15, 3);   srcl[4]  = ROTI(lane15, 4);
  srcl[5]  = ROTI(lane15, 5);   srcl[6]  = ROTI(lane15, 6);
  srcl[7]  = ROTI(lane15, 7);   srcl[8]  = ROTI(lane15, 8);
  srcl[9]  = ROTI(lane15, 9);   srcl[10] = ROTI(lane15, 10);
  srcl[11] = ROTI(lane15, 11);  srcl[12] = ROTI(lane15, 12);
  srcl[13] = ROTI(lane15, 13);  srcl[14] = ROTI(lane15, 14);
  srcl[15] = ROTI(lane15, 15);

  // ---- layer0 ih weights (full dots in-lane) ----
  float wr[IND], wz[IND], wn[IND];
#pragma unroll
  for (int k = 0; k < IND; ++k) {
    wr[k] = wih0[(0 * HD + j) * IND + k];
    wz[k] = wih0[(1 * HD + j) * IND + k];
    wn[k] = wih0[(2 * HD + j) * IND + k];
  }
  // ---- rotation-reindexed weights (slot i multiplies h from src lane) ----
  float R0r[16], R0z[16], R0n[16];   // layer0 hh
  float V1r[16], V1z[16], V1n[16];   // layer1 ih
  float S1r[16], S1z[16], S1n[16];   // layer1 hh
  float FCr[16];                     // fc (rides h2's rotation)
#pragma unroll
  for (int i = 0; i < 16; ++i) {
    const int s  = srcl[i];
    const bool v = (s < HD);
    const int si = v ? s : 0;
    R0r[i] = v ? whh0[(0 * HD + j) * HD + si] : 0.f;
    R0z[i] = v ? whh0[(1 * HD + j) * HD + si] : 0.f;
    R0n[i] = v ? whh0[(2 * HD + j) * HD + si] : 0.f;
    V1r[i] = v ? wih1[(0 * HD + j) * HD + si] : 0.f;
    V1z[i] = v ? wih1[(1 * HD + j) * HD + si] : 0.f;
    V1n[i] = v ? wih1[(2 * HD + j) * HD + si] : 0.f;
    S1r[i] = v ? whh1[(0 * HD + j) * HD + si] : 0.f;
    S1z[i] = v ? whh1[(1 * HD + j) * HD + si] : 0.f;
    S1n[i] = v ? whh1[(2 * HD + j) * HD + si] : 0.f;
    FCr[i] = v ? fcw[si] : 0.f;
  }
  const float br0 = bih0[j] + bhh0[j];
  const float bz0 = bih0[HD + j] + bhh0[HD + j];
  const float bi0 = bih0[2 * HD + j];
  const float bh0 = bhh0[2 * HD + j];
  const float br1 = bih1[j] + bhh1[j];
  const float bz1 = bih1[HD + j] + bhh1[HD + j];
  const float bi1 = bih1[2 * HD + j];
  const float bh1 = bhh1[2 * HD + j];
  const float fb  = fcb[0];

  float h1 = 0.f, h2 = 0.f;
  const float2* xp2 = (const float2*)(x + (size_t)b * Tlen * IND);
  float* outp = out + (size_t)b * Tlen;

  float2 xA[9], xB[9];
#pragma unroll
  for (int i = 0; i < 9; ++i) xA[i] = xp2[i];       // x[0]
#pragma unroll
  for (int i = 0; i < 9; ++i) xB[i] = xp2[9 + i];   // x[1]

#define STEP(XV, TT)                                                         \
  do {                                                                       \
    /* gi0: full dots in-lane on prefetched x */                             \
    float ar = br0, az = bz0, an = bi0;                                      \
    _Pragma("unroll")                                                        \
    for (int i = 0; i < 9; ++i) {                                            \
      ar = fmaf(XV[i].x, wr[2 * i], ar); ar = fmaf(XV[i].y, wr[2 * i + 1], ar); \
      az = fmaf(XV[i].x, wz[2 * i], az); az = fmaf(XV[i].y, wz[2 * i + 1], az); \
      an = fmaf(XV[i].x, wn[2 * i], an); an = fmaf(XV[i].y, wn[2 * i + 1], an); \
    }                                                                        \
    /* hh0: rotate-and-FMA on h1_{t-1} */                                    \
    float hn = bh0;                                                          \
    MV3_ALL(h1, R0r, R0z, R0n, ar, az, hn);                                  \
    /* h2-old block (independent of gates0): hh1 + FC rotations */           \
    float b1r = br1, b1z = bz1, b1n = bh1, oc = fb;                          \
    MV4_ALL(h2, S1r, S1z, S1n, FCr, b1r, b1z, b1n, oc);                      \
    if ((TT) > 0) { if (lane15 == 0) outp[(TT) - 1] = oc; }                  \
    /* gates0 */                                                             \
    float r = sigmoid_f(ar), zg = sigmoid_f(az);                             \
    float n = tanh_f(an + r * hn);                                           \
    h1 = n + zg * (h1 - n);                                                  \
    /* prefetch x[TT+2] (WAR on XV keeps it after gi0) */                    \
    if ((TT) + 2 < Tlen) {                                                   \
      const float2* q_ = xp2 + (size_t)((TT) + 2) * 9;                       \
      _Pragma("unroll")                                                      \
      for (int i = 0; i < 9; ++i) XV[i] = q_[i];                             \
    }                                                                        \
    /* ih1: rotate-and-FMA on fresh h1 */                                    \
    float a1n = bi1;                                                         \
    MV3_ALL(h1, V1r, V1z, V1n, b1r, b1z, a1n);                               \
    float r1 = sigmoid_f(b1r), z1 = sigmoid_f(b1z);                          \
    float n1 = tanh_f(a1n + r1 * b1n);                                       \
    h2 = n1 + z1 * (h2 - n1);                                                \
  } while (0)

  for (int t = 0; t < Tlen; t += 2) {
    STEP(xA, t);
    STEP(xB, t + 1);
  }
#undef STEP

  // epilogue: FC on h2[Tlen-1] via rotation
  {
    float oc = fb;
    oc = fmaf(h2, FCr[0], oc);
#define FCSTEP(i) { float hb_ = ROTF(h2, i); oc = fmaf(hb_, FCr[i], oc); }
    FCSTEP(1)  FCSTEP(2)  FCSTEP(3)  FCSTEP(4)  FCSTEP(5)
    FCSTEP(6)  FCSTEP(7)  FCSTEP(8)  FCSTEP(9)  FCSTEP(10)
    FCSTEP(11) FCSTEP(12) FCSTEP(13) FCSTEP(14) FCSTEP(15)
#undef FCSTEP
    if (lane15 == 0) outp[Tlen - 1] = oc;
  }
}

extern "C" void kernel_launch(void* const* d_in, const int* in_sizes, int n_in,
                              void* d_out, int out_size, void* d_ws, size_t ws_size,
                              hipStream_t stream) {
  (void)in_sizes; (void)n_in; (void)d_ws; (void)ws_size; (void)out_size;
  const float* x    = (const float*)d_in[0];
  const float* wih0 = (const float*)d_in[1];
  const float* whh0 = (const float*)d_in[2];
  const float* bih0 = (const float*)d_in[3];
  const float* bhh0 = (const float*)d_in[4];
  const float* wih1 = (const float*)d_in[5];
  const float* whh1 = (const float*)d_in[6];
  const float* bih1 = (const float*)d_in[7];
  const float* bhh1 = (const float*)d_in[8];
  const float* fcw  = (const float*)d_in[9];
  const float* fcb  = (const float*)d_in[10];
  float* out = (float*)d_out;

  hipLaunchKernelGGL(gru2_dpp, dim3(Bsz / 16), dim3(256), 0, stream,
                     x, wih0, whh0, bih0, bhh0, wih1, whh1, bih1, bhh1, fcw, fcb, out);
}

// Round 9
// 244.975 us; speedup vs baseline: 2.0460x; 1.6370x over previous
//
#include <hip/hip_runtime.h>

#define Bsz 4096
#define Tlen 512
#define IND 18
#define HD 12

typedef float v4f __attribute__((ext_vector_type(4)));

__device__ __forceinline__ float sigmoid_f(float x) {
  return __builtin_amdgcn_rcpf(1.0f + __expf(-x));
}
__device__ __forceinline__ float tanh_f(float x) {
  // tanh(x) = 1 - 2/(1+exp(2x)); saturates correctly at +-inf
  return 1.0f - 2.0f * __builtin_amdgcn_rcpf(1.0f + __expf(2.0f * x));
}

// Producer/consumer layer pipeline, 2 timesteps per barrier tick.
// Block = 128 threads = 2 waves: wave 0 (A) runs layer 0 for 4 batches;
// wave 1 (B) runs layer 1 + FC one tick behind. Each batch owns 16 lanes
// (12 active; lane j computes row j with FULL dots in-lane -> no cross-lane
// reductions). h1 flows A->B via tick-parity double-buffered LDS holding 2
// steps; ONE barrier per tick (257 total vs round-5's 514). A covers its
// LDS round trips with next-step x-projections; B covers read latency with
// hh1+FC dots on register-resident h2 (FC deferred one step).
// 1024 blocks * 2 waves = 2048 waves = 2 waves/SIMD.
extern "C" __global__ void __launch_bounds__(128, 2) gru2_pipe2(
    const float* __restrict__ x,
    const float* __restrict__ wih0, const float* __restrict__ whh0,
    const float* __restrict__ bih0, const float* __restrict__ bhh0,
    const float* __restrict__ wih1, const float* __restrict__ whh1,
    const float* __restrict__ bih1, const float* __restrict__ bhh1,
    const float* __restrict__ fcw, const float* __restrict__ fcb,
    float* __restrict__ out)
{
  const int tid    = threadIdx.x;
  const int lane15 = tid & 15;
  const int g      = (tid >> 4) & 3;     // batch within block (0..3)
  const bool isA   = (tid >> 6) == 0;
  const int b      = blockIdx.x * 4 + g;
  const int j      = (lane15 < HD) ? lane15 : (HD - 1);
  const bool act   = (lane15 < HD);

  __shared__ float h1buf[2][2][4][16];   // [tick parity][step-in-tick][batch][row]
  __shared__ float h2buf[4][16];         // B-private broadcast slot

#define BAR()                                           \
  do {                                                  \
    asm volatile("s_waitcnt lgkmcnt(0)" ::: "memory");  \
    __builtin_amdgcn_s_barrier();                       \
    asm volatile("" ::: "memory");                      \
  } while (0)

  if (isA) {
    // ---------------- A: layer 0, steps 2k, 2k+1 per tick ----------------
    float wr[IND], wz[IND], wn[IND];
#pragma unroll
    for (int k = 0; k < IND; ++k) {
      wr[k] = wih0[(0 * HD + j) * IND + k];
      wz[k] = wih0[(1 * HD + j) * IND + k];
      wn[k] = wih0[(2 * HD + j) * IND + k];
    }
    float ur[HD], uz[HD], un[HD];
#pragma unroll
    for (int k = 0; k < HD; ++k) {
      ur[k] = whh0[(0 * HD + j) * HD + k];
      uz[k] = whh0[(1 * HD + j) * HD + k];
      un[k] = whh0[(2 * HD + j) * HD + k];
    }
    const float br = bih0[j] + bhh0[j];
    const float bz = bih0[HD + j] + bhh0[HD + j];
    const float bi = bih0[2 * HD + j];
    const float bh = bhh0[2 * HD + j];

    float hv[HD];
#pragma unroll
    for (int k = 0; k < HD; ++k) hv[k] = 0.f;
    float h1 = 0.f;

    const float2* xp2 = (const float2*)(x + (size_t)b * Tlen * IND);  // 9 float2/step
    float2 xA9[9], xB9[9];
    float Pr, Pz, Pn, Qr, Qz, Qn;
    {
#pragma unroll
      for (int i = 0; i < 9; ++i) xA9[i] = xp2[i];            // x[0]
      Pr = br; Pz = bz; Pn = bi;
#pragma unroll
      for (int i = 0; i < 9; ++i) {
        Pr = fmaf(xA9[i].x, wr[2*i], Pr); Pr = fmaf(xA9[i].y, wr[2*i+1], Pr);
        Pz = fmaf(xA9[i].x, wz[2*i], Pz); Pz = fmaf(xA9[i].y, wz[2*i+1], Pz);
        Pn = fmaf(xA9[i].x, wn[2*i], Pn); Pn = fmaf(xA9[i].y, wn[2*i+1], Pn);
      }
#pragma unroll
      for (int i = 0; i < 9; ++i) xB9[i] = xp2[9 + i];        // x[1]
#pragma unroll
      for (int i = 0; i < 9; ++i) xA9[i] = xp2[18 + i];       // x[2]
    }

    for (int k = 0; k < 257; ++k) {
      if (k < 256) {
        // ---- step t0 = 2k (projections in P) ----
        float hr = Pr, hz = Pz, hn = bh;
#pragma unroll
        for (int kk = 0; kk < HD; ++kk) {
          hr += hv[kk] * ur[kk]; hz += hv[kk] * uz[kk]; hn += hv[kk] * un[kk];
        }
        float r = sigmoid_f(hr), zg = sigmoid_f(hz);
        float n = tanh_f(Pn + r * hn);
        h1 = n + zg * (h1 - n);
        float* sp0 = &h1buf[k & 1][0][g][0];
        if (act) sp0[j] = h1;
        // Q = proj(x[2k+1]) — covers the LDS round trip
        Qr = br; Qz = bz; Qn = bi;
#pragma unroll
        for (int i = 0; i < 9; ++i) {
          Qr = fmaf(xB9[i].x, wr[2*i], Qr); Qr = fmaf(xB9[i].y, wr[2*i+1], Qr);
          Qz = fmaf(xB9[i].x, wz[2*i], Qz); Qz = fmaf(xB9[i].y, wz[2*i+1], Qz);
          Qn = fmaf(xB9[i].x, wn[2*i], Qn); Qn = fmaf(xB9[i].y, wn[2*i+1], Qn);
        }
        {
          v4f a0 = *(const v4f*)(sp0 + 0);
          v4f a1 = *(const v4f*)(sp0 + 4);
          v4f a2 = *(const v4f*)(sp0 + 8);
          if (k <= 254) {  // load x[2k+3] (consumed next tick)
            const float2* p = xp2 + (size_t)(2 * k + 3) * 9;
#pragma unroll
            for (int i = 0; i < 9; ++i) xB9[i] = p[i];
          }
#pragma unroll
          for (int kk = 0; kk < 4; ++kk) { hv[kk] = a0[kk]; hv[4+kk] = a1[kk]; hv[8+kk] = a2[kk]; }
        }
        // ---- step t1 = 2k+1 (projections in Q) ----
        hr = Qr; hz = Qz; hn = bh;
#pragma unroll
        for (int kk = 0; kk < HD; ++kk) {
          hr += hv[kk] * ur[kk]; hz += hv[kk] * uz[kk]; hn += hv[kk] * un[kk];
        }
        r = sigmoid_f(hr); zg = sigmoid_f(hz);
        n = tanh_f(Qn + r * hn);
        h1 = n + zg * (h1 - n);
        float* sp1 = &h1buf[k & 1][1][g][0];
        if (act) sp1[j] = h1;
        // P = proj(x[2k+2]) — covers the LDS round trip
        Pr = br; Pz = bz; Pn = bi;
#pragma unroll
        for (int i = 0; i < 9; ++i) {
          Pr = fmaf(xA9[i].x, wr[2*i], Pr); Pr = fmaf(xA9[i].y, wr[2*i+1], Pr);
          Pz = fmaf(xA9[i].x, wz[2*i], Pz); Pz = fmaf(xA9[i].y, wz[2*i+1], Pz);
          Pn = fmaf(xA9[i].x, wn[2*i], Pn); Pn = fmaf(xA9[i].y, wn[2*i+1], Pn);
        }
        {
          v4f a0 = *(const v4f*)(sp1 + 0);
          v4f a1 = *(const v4f*)(sp1 + 4);
          v4f a2 = *(const v4f*)(sp1 + 8);
          if (k <= 253) {  // load x[2k+4]
            const float2* p = xp2 + (size_t)(2 * k + 4) * 9;
#pragma unroll
            for (int i = 0; i < 9; ++i) xA9[i] = p[i];
          }
#pragma unroll
          for (int kk = 0; kk < 4; ++kk) { hv[kk] = a0[kk]; hv[4+kk] = a1[kk]; hv[8+kk] = a2[kk]; }
        }
      }
      BAR();
    }
  } else {
    // ---------------- B: layer 1 + FC, steps 2k-2, 2k-1 per tick ----------------
    float vr[HD], vz[HD], vn[HD], ur[HD], uz[HD], un[HD], fw[HD];
#pragma unroll
    for (int k = 0; k < HD; ++k) {
      vr[k] = wih1[(0 * HD + j) * HD + k];
      vz[k] = wih1[(1 * HD + j) * HD + k];
      vn[k] = wih1[(2 * HD + j) * HD + k];
      ur[k] = whh1[(0 * HD + j) * HD + k];
      uz[k] = whh1[(1 * HD + j) * HD + k];
      un[k] = whh1[(2 * HD + j) * HD + k];
      fw[k] = fcw[k];
    }
    const float br = bih1[j] + bhh1[j];
    const float bz = bih1[HD + j] + bhh1[HD + j];
    const float bi = bih1[2 * HD + j];
    const float bh = bhh1[2 * HD + j];
    const float fb = fcb[0];

    float hw[HD];
#pragma unroll
    for (int k = 0; k < HD; ++k) hw[k] = 0.f;
    float h2 = 0.f;
    float* outp = out + (size_t)b * Tlen;

    for (int k = 0; k < 257; ++k) {
      if (k >= 1) {
        const int s0 = 2 * k - 2;
        const float* sp0 = &h1buf[(k - 1) & 1][0][g][0];
        v4f a0 = *(const v4f*)(sp0 + 0);   // h1[s0], ready post-barrier
        v4f a1 = *(const v4f*)(sp0 + 4);
        v4f a2 = *(const v4f*)(sp0 + 8);
        // hh1 + FC dots on hw = h2[s0-1] (covers the h1 read)
        float hr = br, hz = bz, hn = bh, oc = fb;
#pragma unroll
        for (int kk = 0; kk < HD; ++kk) {
          hr += hw[kk] * ur[kk]; hz += hw[kk] * uz[kk];
          hn += hw[kk] * un[kk]; oc += hw[kk] * fw[kk];
        }
        if (k >= 2 && lane15 == 0) outp[s0 - 1] = oc;   // FC(h2[s0-1])
        float g1[HD];
#pragma unroll
        for (int kk = 0; kk < 4; ++kk) { g1[kk] = a0[kk]; g1[4+kk] = a1[kk]; g1[8+kk] = a2[kk]; }
        float in1 = bi;
#pragma unroll
        for (int kk = 0; kk < HD; ++kk) {
          hr += g1[kk] * vr[kk]; hz += g1[kk] * vz[kk]; in1 += g1[kk] * vn[kk];
        }
        float r = sigmoid_f(hr), zg = sigmoid_f(hz);
        float n = tanh_f(in1 + r * hn);
        h2 = n + zg * (h2 - n);
        float* sq = &h2buf[g][0];
        if (act) sq[j] = h2;
        // issue h1[s0+1] read + hw readback; cover with ih1 dots
        const float* sp1 = &h1buf[(k - 1) & 1][1][g][0];
        v4f b0 = *(const v4f*)(sp1 + 0);
        v4f b1 = *(const v4f*)(sp1 + 4);
        v4f b2 = *(const v4f*)(sp1 + 8);
        v4f c0 = *(const v4f*)(sq + 0);
        v4f c1 = *(const v4f*)(sq + 4);
        v4f c2 = *(const v4f*)(sq + 8);
        float g2[HD];
#pragma unroll
        for (int kk = 0; kk < 4; ++kk) { g2[kk] = b0[kk]; g2[4+kk] = b1[kk]; g2[8+kk] = b2[kk]; }
        float hr2 = br, hz2 = bz, in2 = bi;
#pragma unroll
        for (int kk = 0; kk < HD; ++kk) {
          hr2 += g2[kk] * vr[kk]; hz2 += g2[kk] * vz[kk]; in2 += g2[kk] * vn[kk];
        }
#pragma unroll
        for (int kk = 0; kk < 4; ++kk) { hw[kk] = c0[kk]; hw[4+kk] = c1[kk]; hw[8+kk] = c2[kk]; }
        float hn2 = bh, oc2 = fb;
#pragma unroll
        for (int kk = 0; kk < HD; ++kk) {
          hr2 += hw[kk] * ur[kk]; hz2 += hw[kk] * uz[kk];
          hn2 += hw[kk] * un[kk]; oc2 += hw[kk] * fw[kk];
        }
        if (lane15 == 0) outp[s0] = oc2;                // FC(h2[s0])
        float r2 = sigmoid_f(hr2), zg2 = sigmoid_f(hz2);
        float n2 = tanh_f(in2 + r2 * hn2);
        h2 = n2 + zg2 * (h2 - n2);
        if (act) sq[j] = h2;
        v4f d0 = *(const v4f*)(sq + 0);
        v4f d1 = *(const v4f*)(sq + 4);
        v4f d2 = *(const v4f*)(sq + 8);
#pragma unroll
        for (int kk = 0; kk < 4; ++kk) { hw[kk] = d0[kk]; hw[4+kk] = d1[kk]; hw[8+kk] = d2[kk]; }
      }
      BAR();
    }
    // epilogue: FC on h2[Tlen-1]
    float oc = fb;
#pragma unroll
    for (int kk = 0; kk < HD; ++kk) oc += hw[kk] * fw[kk];
    if (lane15 == 0) outp[Tlen - 1] = oc;
  }
#undef BAR
}

extern "C" void kernel_launch(void* const* d_in, const int* in_sizes, int n_in,
                              void* d_out, int out_size, void* d_ws, size_t ws_size,
                              hipStream_t stream) {
  (void)in_sizes; (void)n_in; (void)d_ws; (void)ws_size; (void)out_size;
  const float* x    = (const float*)d_in[0];
  const float* wih0 = (const float*)d_in[1];
  const float* whh0 = (const float*)d_in[2];
  const float* bih0 = (const float*)d_in[3];
  const float* bhh0 = (const float*)d_in[4];
  const float* wih1 = (const float*)d_in[5];
  const float* whh1 = (const float*)d_in[6];
  const float* bih1 = (const float*)d_in[7];
  const float* bhh1 = (const float*)d_in[8];
  const float* fcw  = (const float*)d_in[9];
  const float* fcb  = (const float*)d_in[10];
  float* out = (float*)d_out;

  hipLaunchKernelGGL(gru2_pipe2, dim3(Bsz / 4), dim3(128), 0, stream,
                     x, wih0, whh0, bih0, bhh0, wih1, whh1, bih1, bhh1, fcw, fcb, out);
}

// Round 10
// 182.609 us; speedup vs baseline: 2.7448x; 1.3415x over previous
//
#include <hip/hip_runtime.h>

#define Bsz 4096
#define Tlen 512
#define IND 18
#define HD 12
#define L2E 1.44269504088896340736f

typedef float v2 __attribute__((ext_vector_type(2)));
typedef float v4f __attribute__((ext_vector_type(4)));

__device__ __forceinline__ v2 pkfma(v2 a, v2 b, v2 c) {
  return __builtin_elementwise_fma(a, b, c);  // v_pk_fma_f32
}
__device__ __forceinline__ v2 vlo(v4f a) { return (v2){a.x, a.y}; }
__device__ __forceinline__ v2 vhi(v4f a) { return (v2){a.z, a.w}; }
// args pre-scaled: sigmoid arg by log2e, tanh arg by 2*log2e (folded into weights)
__device__ __forceinline__ float sigmoid_s(float x) {
  return __builtin_amdgcn_rcpf(1.f + __builtin_amdgcn_exp2f(-x));
}
__device__ __forceinline__ float tanh_s(float x) {
  return 1.f - 2.f * __builtin_amdgcn_rcpf(1.f + __builtin_amdgcn_exp2f(x));
}

// Producer/consumer layer pipeline, 4 timesteps per barrier tick (129 barriers).
// Block = 128 thr = 2 waves: A (layer 0, 4 batches) / B (layer 1 + FC, one tick
// behind). 16 lanes per batch, full dots in-lane, all dots packed into
// v_pk_fma_f32; exp2-prescaled gate weights. h1 flows A->B via tick-parity
// double-buffered LDS (4 steps per buffer). 1024 blocks * 2 = 2048 waves = 2/SIMD.
extern "C" __global__ void __launch_bounds__(128, 2) gru2_pipe4(
    const float* __restrict__ x,
    const float* __restrict__ wih0, const float* __restrict__ whh0,
    const float* __restrict__ bih0, const float* __restrict__ bhh0,
    const float* __restrict__ wih1, const float* __restrict__ whh1,
    const float* __restrict__ bih1, const float* __restrict__ bhh1,
    const float* __restrict__ fcw, const float* __restrict__ fcb,
    float* __restrict__ out)
{
  const int tid    = threadIdx.x;
  const int lane15 = tid & 15;
  const int g      = (tid >> 4) & 3;     // batch within block (0..3)
  const bool isA   = (tid >> 6) == 0;
  const int b      = blockIdx.x * 4 + g;
  const int j      = (lane15 < HD) ? lane15 : (HD - 1);
  const bool act   = (lane15 < HD);

  __shared__ float h1buf[2][4][4][16];   // [tick parity][step-in-tick][batch][row]
  __shared__ float h2buf[4][16];         // B-private broadcast slot

#define BAR()                                           \
  do {                                                  \
    asm volatile("s_waitcnt lgkmcnt(0)" ::: "memory");  \
    __builtin_amdgcn_s_barrier();                       \
    asm volatile("" ::: "memory");                      \
  } while (0)

  if (isA) {
    // ---------------- A: layer 0, steps 4k..4k+3 per tick ----------------
    v2 wr2[9], wz2[9], wn2[9];           // ih0 rows j/12+j/24+j, k-pairs (scaled)
#pragma unroll
    for (int i = 0; i < 9; ++i) {
      wr2[i] = (v2){ wih0[(0*HD+j)*IND + 2*i] * L2E,       wih0[(0*HD+j)*IND + 2*i+1] * L2E };
      wz2[i] = (v2){ wih0[(1*HD+j)*IND + 2*i] * L2E,       wih0[(1*HD+j)*IND + 2*i+1] * L2E };
      wn2[i] = (v2){ wih0[(2*HD+j)*IND + 2*i] * (2*L2E),   wih0[(2*HD+j)*IND + 2*i+1] * (2*L2E) };
    }
    v2 ur2[6], uz2[6], un2[6];           // hh0 (scaled)
#pragma unroll
    for (int i = 0; i < 6; ++i) {
      ur2[i] = (v2){ whh0[(0*HD+j)*HD + 2*i] * L2E,      whh0[(0*HD+j)*HD + 2*i+1] * L2E };
      uz2[i] = (v2){ whh0[(1*HD+j)*HD + 2*i] * L2E,      whh0[(1*HD+j)*HD + 2*i+1] * L2E };
      un2[i] = (v2){ whh0[(2*HD+j)*HD + 2*i] * (2*L2E),  whh0[(2*HD+j)*HD + 2*i+1] * (2*L2E) };
    }
    const float brS = (bih0[j] + bhh0[j]) * L2E;
    const float bzS = (bih0[HD+j] + bhh0[HD+j]) * L2E;
    const float biS = bih0[2*HD+j] * (2*L2E);
    const float bhS = bhh0[2*HD+j] * (2*L2E);

    v2 hv2[6];
#pragma unroll
    for (int i = 0; i < 6; ++i) hv2[i] = (v2){0.f, 0.f};
    float h1 = 0.f;

    const v2* xp2 = (const v2*)(x + (size_t)b * Tlen * IND);  // 9 v2 per step
    v2 xb0[9], xb1[9];
    v2 Pr2, Pz2, Pn2;
    {
#pragma unroll
      for (int i = 0; i < 9; ++i) xb0[i] = xp2[i];            // x[0]
      Pr2 = (v2){brS, 0.f}; Pz2 = (v2){bzS, 0.f}; Pn2 = (v2){biS, 0.f};
#pragma unroll
      for (int i = 0; i < 9; ++i) {
        Pr2 = pkfma(xb0[i], wr2[i], Pr2);
        Pz2 = pkfma(xb0[i], wz2[i], Pz2);
        Pn2 = pkfma(xb0[i], wn2[i], Pn2);
      }
#pragma unroll
      for (int i = 0; i < 9; ++i) xb1[i] = xp2[9 + i];        // x[1]
#pragma unroll
      for (int i = 0; i < 9; ++i) xb0[i] = xp2[18 + i];       // x[2]
    }

// before step T: P = proj(x[T]); XN holds x[T+1]; other buf holds x[T+2].
#define ASTEP(T, XN)                                                          \
    do {                                                                      \
      v2 ra2 = Pr2, za2 = Pz2, ha2 = (v2){bhS, 0.f};                          \
      _Pragma("unroll")                                                       \
      for (int i = 0; i < 6; ++i) {                                           \
        ra2 = pkfma(hv2[i], ur2[i], ra2);                                     \
        za2 = pkfma(hv2[i], uz2[i], za2);                                     \
        ha2 = pkfma(hv2[i], un2[i], ha2);                                     \
      }                                                                       \
      float ar = ra2.x + ra2.y, az = za2.x + za2.y;                           \
      float hn = ha2.x + ha2.y, an = Pn2.x + Pn2.y;                           \
      float r = sigmoid_s(ar), zg = sigmoid_s(az);                            \
      float n = tanh_s(an + r * hn);                                          \
      h1 = n + zg * (h1 - n);                                                 \
      float* sp = &h1buf[k & 1][(T) & 3][g][0];                               \
      if (act) sp[j] = h1;                                                    \
      /* next-step projections: cover the LDS round trip */                   \
      Pr2 = (v2){brS, 0.f}; Pz2 = (v2){bzS, 0.f}; Pn2 = (v2){biS, 0.f};       \
      _Pragma("unroll")                                                       \
      for (int i = 0; i < 9; ++i) {                                           \
        Pr2 = pkfma(XN[i], wr2[i], Pr2);                                      \
        Pz2 = pkfma(XN[i], wz2[i], Pz2);                                      \
        Pn2 = pkfma(XN[i], wn2[i], Pn2);                                      \
      }                                                                       \
      v4f a0 = *(const v4f*)(sp + 0);                                         \
      v4f a1 = *(const v4f*)(sp + 4);                                         \
      v4f a2 = *(const v4f*)(sp + 8);                                         \
      if ((T) + 3 < Tlen) {                                                   \
        const v2* p_ = xp2 + (size_t)((T) + 3) * 9;                           \
        _Pragma("unroll")                                                     \
        for (int i = 0; i < 9; ++i) XN[i] = p_[i];                            \
      }                                                                       \
      hv2[0] = vlo(a0); hv2[1] = vhi(a0);                                     \
      hv2[2] = vlo(a1); hv2[3] = vhi(a1);                                     \
      hv2[4] = vlo(a2); hv2[5] = vhi(a2);                                     \
    } while (0)

    for (int k = 0; k < 129; ++k) {
      if (k < 128) {
        const int t0 = 4 * k;
        ASTEP(t0 + 0, xb1);
        ASTEP(t0 + 1, xb0);
        ASTEP(t0 + 2, xb1);
        ASTEP(t0 + 3, xb0);
      }
      BAR();
    }
#undef ASTEP
  } else {
    // ---------------- B: layer 1 + FC, steps 4(k-1)..4(k-1)+3 ----------------
    v2 vr2[6], vz2[6], vn2[6];           // ih1 (scaled)
    v2 sr2[6], sz2[6], sn2[6];           // hh1 (scaled)
    v2 fw2[6];                           // fc (unscaled)
#pragma unroll
    for (int i = 0; i < 6; ++i) {
      vr2[i] = (v2){ wih1[(0*HD+j)*HD + 2*i] * L2E,      wih1[(0*HD+j)*HD + 2*i+1] * L2E };
      vz2[i] = (v2){ wih1[(1*HD+j)*HD + 2*i] * L2E,      wih1[(1*HD+j)*HD + 2*i+1] * L2E };
      vn2[i] = (v2){ wih1[(2*HD+j)*HD + 2*i] * (2*L2E),  wih1[(2*HD+j)*HD + 2*i+1] * (2*L2E) };
      sr2[i] = (v2){ whh1[(0*HD+j)*HD + 2*i] * L2E,      whh1[(0*HD+j)*HD + 2*i+1] * L2E };
      sz2[i] = (v2){ whh1[(1*HD+j)*HD + 2*i] * L2E,      whh1[(1*HD+j)*HD + 2*i+1] * L2E };
      sn2[i] = (v2){ whh1[(2*HD+j)*HD + 2*i] * (2*L2E),  whh1[(2*HD+j)*HD + 2*i+1] * (2*L2E) };
      fw2[i] = (v2){ fcw[2*i], fcw[2*i+1] };
    }
    const float br1S = (bih1[j] + bhh1[j]) * L2E;
    const float bz1S = (bih1[HD+j] + bhh1[HD+j]) * L2E;
    const float bi1S = bih1[2*HD+j] * (2*L2E);
    const float bh1S = bhh1[2*HD+j] * (2*L2E);
    const float fb   = fcb[0];

    v2 hw2[6];
#pragma unroll
    for (int i = 0; i < 6; ++i) hw2[i] = (v2){0.f, 0.f};
    float h2 = 0.f;
    float* outp = out + (size_t)b * Tlen;

#define BSTEP(S)                                                              \
    do {                                                                      \
      const float* sp = &h1buf[(k - 1) & 1][(S) & 3][g][0];                   \
      v4f a0 = *(const v4f*)(sp + 0);                                         \
      v4f a1 = *(const v4f*)(sp + 4);                                         \
      v4f a2 = *(const v4f*)(sp + 8);                                         \
      /* hh1 + FC on hw2 = h2[S-1]: covers the h1 read */                     \
      v2 ra = (v2){br1S, 0.f}, za = (v2){bz1S, 0.f};                          \
      v2 ha = (v2){bh1S, 0.f}, oa = (v2){fb, 0.f};                            \
      _Pragma("unroll")                                                       \
      for (int i = 0; i < 6; ++i) {                                           \
        ra = pkfma(hw2[i], sr2[i], ra);                                       \
        za = pkfma(hw2[i], sz2[i], za);                                       \
        ha = pkfma(hw2[i], sn2[i], ha);                                       \
        oa = pkfma(hw2[i], fw2[i], oa);                                       \
      }                                                                       \
      if ((S) >= 1 && lane15 == 0) outp[(S) - 1] = oa.x + oa.y;               \
      v2 g0 = vlo(a0), g1v = vhi(a0), g2v = vlo(a1);                          \
      v2 g3 = vhi(a1), g4 = vlo(a2), g5 = vhi(a2);                            \
      v2 ia = (v2){bi1S, 0.f};                                                \
      ra = pkfma(g0, vr2[0], ra);  za = pkfma(g0, vz2[0], za);  ia = pkfma(g0, vn2[0], ia);   \
      ra = pkfma(g1v, vr2[1], ra); za = pkfma(g1v, vz2[1], za); ia = pkfma(g1v, vn2[1], ia);  \
      ra = pkfma(g2v, vr2[2], ra); za = pkfma(g2v, vz2[2], za); ia = pkfma(g2v, vn2[2], ia);  \
      ra = pkfma(g3, vr2[3], ra);  za = pkfma(g3, vz2[3], za);  ia = pkfma(g3, vn2[3], ia);   \
      ra = pkfma(g4, vr2[4], ra);  za = pkfma(g4, vz2[4], za);  ia = pkfma(g4, vn2[4], ia);   \
      ra = pkfma(g5, vr2[5], ra);  za = pkfma(g5, vz2[5], za);  ia = pkfma(g5, vn2[5], ia);   \
      float ar = ra.x + ra.y, az = za.x + za.y;                               \
      float hn = ha.x + ha.y, an = ia.x + ia.y;                               \
      float r = sigmoid_s(ar), zg = sigmoid_s(az);                            \
      float n = tanh_s(an + r * hn);                                          \
      h2 = n + zg * (h2 - n);                                                 \
      float* sq = &h2buf[g][0];                                               \
      if (act) sq[j] = h2;                                                    \
      v4f c0 = *(const v4f*)(sq + 0);                                         \
      v4f c1 = *(const v4f*)(sq + 4);                                         \
      v4f c2 = *(const v4f*)(sq + 8);                                         \
      hw2[0] = vlo(c0); hw2[1] = vhi(c0);                                     \
      hw2[2] = vlo(c1); hw2[3] = vhi(c1);                                     \
      hw2[4] = vlo(c2); hw2[5] = vhi(c2);                                     \
    } while (0)

    for (int k = 0; k < 129; ++k) {
      if (k >= 1) {
        const int s0 = 4 * (k - 1);
        BSTEP(s0 + 0);
        BSTEP(s0 + 1);
        BSTEP(s0 + 2);
        BSTEP(s0 + 3);
      }
      BAR();
    }
#undef BSTEP
    // epilogue: FC on h2[Tlen-1]
    v2 oa = (v2){fb, 0.f};
#pragma unroll
    for (int i = 0; i < 6; ++i) oa = pkfma(hw2[i], fw2[i], oa);
    if (lane15 == 0) outp[Tlen - 1] = oa.x + oa.y;
  }
#undef BAR
}

extern "C" void kernel_launch(void* const* d_in, const int* in_sizes, int n_in,
                              void* d_out, int out_size, void* d_ws, size_t ws_size,
                              hipStream_t stream) {
  (void)in_sizes; (void)n_in; (void)d_ws; (void)ws_size; (void)out_size;
  const float* x    = (const float*)d_in[0];
  const float* wih0 = (const float*)d_in[1];
  const float* whh0 = (const float*)d_in[2];
  const float* bih0 = (const float*)d_in[3];
  const float* bhh0 = (const float*)d_in[4];
  const float* wih1 = (const float*)d_in[5];
  const float* whh1 = (const float*)d_in[6];
  const float* bih1 = (const float*)d_in[7];
  const float* bhh1 = (const float*)d_in[8];
  const float* fcw  = (const float*)d_in[9];
  const float* fcb  = (const float*)d_in[10];
  float* out = (float*)d_out;

  hipLaunchKernelGGL(gru2_pipe4, dim3(Bsz / 4), dim3(128), 0, stream,
                     x, wih0, whh0, bih0, bhh0, wih1, whh1, bih1, bhh1, fcw, fcb, out);
}

// Round 11
// 179.487 us; speedup vs baseline: 2.7925x; 1.0174x over previous
//
#include <hip/hip_runtime.h>

#define Bsz 4096
#define Tlen 512
#define IND 18
#define HD 12
#define L2E 1.44269504088896340736f

typedef float v2 __attribute__((ext_vector_type(2)));
typedef float v4f __attribute__((ext_vector_type(4)));

__device__ __forceinline__ v2 pkfma(v2 a, v2 b, v2 c) {
  return __builtin_elementwise_fma(a, b, c);  // v_pk_fma_f32
}
__device__ __forceinline__ v2 vlo(v4f a) { return (v2){a.x, a.y}; }
__device__ __forceinline__ v2 vhi(v4f a) { return (v2){a.z, a.w}; }
// args pre-scaled: sigmoid arg by log2e, tanh arg by 2*log2e (folded into weights)
__device__ __forceinline__ float sigmoid_s(float x) {
  return __builtin_amdgcn_rcpf(1.f + __builtin_amdgcn_exp2f(-x));
}
__device__ __forceinline__ float tanh_s(float x) {
  return 1.f - 2.f * __builtin_amdgcn_rcpf(1.f + __builtin_amdgcn_exp2f(x));
}

// Producer/consumer layer pipeline, 4 timesteps per barrier tick (129 barriers).
// Same math as round 10 (packed v_pk_fma_f32 dots, exp2-prescaled weights);
// schedule fixed to hide LDS latency:
//  - A: h1 readback issued immediately after the write, consumed AFTER the
//    27-pk projection block (~60+ cyc cover, was ~0).
//  - B: h1 reads prefetched one full step ahead (qa/qb ping-pong); each step
//    runs ih1 (independent) BEFORE hh1+FC so the h2 readback of the previous
//    step is covered; step 0 runs hh1-first to cover its fresh q reads.
//  - no exec-mask toggles on LDS writes: sp[lane15] (slots 12-15 never read);
//    FC stores deferred to one masked block per tick.
// 1024 blocks * 2 waves = 2048 waves = 2 waves/SIMD.
extern "C" __global__ void __launch_bounds__(128, 2) gru2_pipe5(
    const float* __restrict__ x,
    const float* __restrict__ wih0, const float* __restrict__ whh0,
    const float* __restrict__ bih0, const float* __restrict__ bhh0,
    const float* __restrict__ wih1, const float* __restrict__ whh1,
    const float* __restrict__ bih1, const float* __restrict__ bhh1,
    const float* __restrict__ fcw, const float* __restrict__ fcb,
    float* __restrict__ out)
{
  const int tid    = threadIdx.x;
  const int lane15 = tid & 15;
  const int g      = (tid >> 4) & 3;     // batch within block (0..3)
  const bool isA   = (tid >> 6) == 0;
  const int b      = blockIdx.x * 4 + g;
  const int j      = (lane15 < HD) ? lane15 : (HD - 1);

  __shared__ float h1buf[2][4][4][16];   // [tick parity][step-in-tick][batch][row]
  __shared__ float h2buf[4][16];         // B-private broadcast slot

#define BAR()                                           \
  do {                                                  \
    asm volatile("s_waitcnt lgkmcnt(0)" ::: "memory");  \
    __builtin_amdgcn_s_barrier();                       \
    asm volatile("" ::: "memory");                      \
  } while (0)

  if (isA) {
    // ---------------- A: layer 0, steps 4k..4k+3 per tick ----------------
    v2 wr2[9], wz2[9], wn2[9];           // ih0 rows j/12+j/24+j, k-pairs (scaled)
#pragma unroll
    for (int i = 0; i < 9; ++i) {
      wr2[i] = (v2){ wih0[(0*HD+j)*IND + 2*i] * L2E,       wih0[(0*HD+j)*IND + 2*i+1] * L2E };
      wz2[i] = (v2){ wih0[(1*HD+j)*IND + 2*i] * L2E,       wih0[(1*HD+j)*IND + 2*i+1] * L2E };
      wn2[i] = (v2){ wih0[(2*HD+j)*IND + 2*i] * (2*L2E),   wih0[(2*HD+j)*IND + 2*i+1] * (2*L2E) };
    }
    v2 ur2[6], uz2[6], un2[6];           // hh0 (scaled)
#pragma unroll
    for (int i = 0; i < 6; ++i) {
      ur2[i] = (v2){ whh0[(0*HD+j)*HD + 2*i] * L2E,      whh0[(0*HD+j)*HD + 2*i+1] * L2E };
      uz2[i] = (v2){ whh0[(1*HD+j)*HD + 2*i] * L2E,      whh0[(1*HD+j)*HD + 2*i+1] * L2E };
      un2[i] = (v2){ whh0[(2*HD+j)*HD + 2*i] * (2*L2E),  whh0[(2*HD+j)*HD + 2*i+1] * (2*L2E) };
    }
    const float brS = (bih0[j] + bhh0[j]) * L2E;
    const float bzS = (bih0[HD+j] + bhh0[HD+j]) * L2E;
    const float biS = bih0[2*HD+j] * (2*L2E);
    const float bhS = bhh0[2*HD+j] * (2*L2E);

    v2 hv2[6];
#pragma unroll
    for (int i = 0; i < 6; ++i) hv2[i] = (v2){0.f, 0.f};
    float h1 = 0.f;

    const v2* xp2 = (const v2*)(x + (size_t)b * Tlen * IND);  // 9 v2 per step
    v2 xb0[9], xb1[9];
    v2 Pr2, Pz2, Pn2;
    {
#pragma unroll
      for (int i = 0; i < 9; ++i) xb0[i] = xp2[i];            // x[0]
      Pr2 = (v2){brS, 0.f}; Pz2 = (v2){bzS, 0.f}; Pn2 = (v2){biS, 0.f};
#pragma unroll
      for (int i = 0; i < 9; ++i) {
        Pr2 = pkfma(xb0[i], wr2[i], Pr2);
        Pz2 = pkfma(xb0[i], wz2[i], Pz2);
        Pn2 = pkfma(xb0[i], wn2[i], Pn2);
      }
#pragma unroll
      for (int i = 0; i < 9; ++i) xb1[i] = xp2[9 + i];        // x[1]
#pragma unroll
      for (int i = 0; i < 9; ++i) xb0[i] = xp2[18 + i];       // x[2]
    }

// before step T: P = proj(x[T]); XN holds x[T+1]; other buf holds x[T+2].
#define ASTEP(T, XN)                                                          \
    do {                                                                      \
      v2 ra2 = Pr2, za2 = Pz2, ha2 = (v2){bhS, 0.f};                          \
      _Pragma("unroll")                                                       \
      for (int i = 0; i < 6; ++i) {                                           \
        ra2 = pkfma(hv2[i], ur2[i], ra2);                                     \
        za2 = pkfma(hv2[i], uz2[i], za2);                                     \
        ha2 = pkfma(hv2[i], un2[i], ha2);                                     \
      }                                                                       \
      float ar = ra2.x + ra2.y, az = za2.x + za2.y;                           \
      float hn = ha2.x + ha2.y, an = Pn2.x + Pn2.y;                           \
      float r = sigmoid_s(ar), zg = sigmoid_s(az);                            \
      float n = tanh_s(an + r * hn);                                          \
      h1 = n + zg * (h1 - n);                                                 \
      float* sp = &h1buf[k & 1][(T) & 3][g][0];                               \
      sp[lane15] = h1;      /* slots 12-15 hold clamped row 11, never read */ \
      v4f a0 = ((const v4f*)sp)[0];   /* readback issued RIGHT after write */ \
      v4f a1 = ((const v4f*)sp)[1];                                           \
      v4f a2 = ((const v4f*)sp)[2];                                           \
      /* next-step projections cover the ds_read latency */                   \
      Pr2 = (v2){brS, 0.f}; Pz2 = (v2){bzS, 0.f}; Pn2 = (v2){biS, 0.f};       \
      _Pragma("unroll")                                                       \
      for (int i = 0; i < 9; ++i) {                                           \
        Pr2 = pkfma(XN[i], wr2[i], Pr2);                                      \
        Pz2 = pkfma(XN[i], wz2[i], Pz2);                                      \
        Pn2 = pkfma(XN[i], wn2[i], Pn2);                                      \
      }                                                                       \
      if ((T) + 3 < Tlen) {                                                   \
        const v2* p_ = xp2 + (size_t)((T) + 3) * 9;                           \
        _Pragma("unroll")                                                     \
        for (int i = 0; i < 9; ++i) XN[i] = p_[i];                            \
      }                                                                       \
      hv2[0] = vlo(a0); hv2[1] = vhi(a0);                                     \
      hv2[2] = vlo(a1); hv2[3] = vhi(a1);                                     \
      hv2[4] = vlo(a2); hv2[5] = vhi(a2);                                     \
    } while (0)

    for (int k = 0; k < 129; ++k) {
      if (k < 128) {
        const int t0 = 4 * k;
        ASTEP(t0 + 0, xb1);
        ASTEP(t0 + 1, xb0);
        ASTEP(t0 + 2, xb1);
        ASTEP(t0 + 3, xb0);
      }
      BAR();
    }
#undef ASTEP
  } else {
    // ---------------- B: layer 1 + FC, steps 4(k-1)..4(k-1)+3 ----------------
    v2 vr2[6], vz2[6], vn2[6];           // ih1 (scaled)
    v2 sr2[6], sz2[6], sn2[6];           // hh1 (scaled)
    v2 fw2[6];                           // fc (unscaled)
#pragma unroll
    for (int i = 0; i < 6; ++i) {
      vr2[i] = (v2){ wih1[(0*HD+j)*HD + 2*i] * L2E,      wih1[(0*HD+j)*HD + 2*i+1] * L2E };
      vz2[i] = (v2){ wih1[(1*HD+j)*HD + 2*i] * L2E,      wih1[(1*HD+j)*HD + 2*i+1] * L2E };
      vn2[i] = (v2){ wih1[(2*HD+j)*HD + 2*i] * (2*L2E),  wih1[(2*HD+j)*HD + 2*i+1] * (2*L2E) };
      sr2[i] = (v2){ whh1[(0*HD+j)*HD + 2*i] * L2E,      whh1[(0*HD+j)*HD + 2*i+1] * L2E };
      sz2[i] = (v2){ whh1[(1*HD+j)*HD + 2*i] * L2E,      whh1[(1*HD+j)*HD + 2*i+1] * L2E };
      sn2[i] = (v2){ whh1[(2*HD+j)*HD + 2*i] * (2*L2E),  whh1[(2*HD+j)*HD + 2*i+1] * (2*L2E) };
      fw2[i] = (v2){ fcw[2*i], fcw[2*i+1] };
    }
    const float br1S = (bih1[j] + bhh1[j]) * L2E;
    const float bz1S = (bih1[HD+j] + bhh1[HD+j]) * L2E;
    const float bi1S = bih1[2*HD+j] * (2*L2E);
    const float bh1S = bhh1[2*HD+j] * (2*L2E);
    const float fb   = fcb[0];

    v2 hw2[6];
#pragma unroll
    for (int i = 0; i < 6; ++i) hw2[i] = (v2){0.f, 0.f};
    float h2 = 0.f;
    float* outp = out + (size_t)b * Tlen;
    float* sq = &h2buf[g][0];

#define READQ(Q, SIDX)                                                        \
    { const float* sp_ = &h1buf[par][SIDX][g][0];                             \
      Q##0 = ((const v4f*)sp_)[0];                                            \
      Q##1 = ((const v4f*)sp_)[1];                                            \
      Q##2 = ((const v4f*)sp_)[2]; }

#define IH1(Q, ra, za, ia)                                                    \
    ra = pkfma(vlo(Q##0), vr2[0], ra); za = pkfma(vlo(Q##0), vz2[0], za); ia = pkfma(vlo(Q##0), vn2[0], ia); \
    ra = pkfma(vhi(Q##0), vr2[1], ra); za = pkfma(vhi(Q##0), vz2[1], za); ia = pkfma(vhi(Q##0), vn2[1], ia); \
    ra = pkfma(vlo(Q##1), vr2[2], ra); za = pkfma(vlo(Q##1), vz2[2], za); ia = pkfma(vlo(Q##1), vn2[2], ia); \
    ra = pkfma(vhi(Q##1), vr2[3], ra); za = pkfma(vhi(Q##1), vz2[3], za); ia = pkfma(vhi(Q##1), vn2[3], ia); \
    ra = pkfma(vlo(Q##2), vr2[4], ra); za = pkfma(vlo(Q##2), vz2[4], za); ia = pkfma(vlo(Q##2), vn2[4], ia); \
    ra = pkfma(vhi(Q##2), vr2[5], ra); za = pkfma(vhi(Q##2), vz2[5], za); ia = pkfma(vhi(Q##2), vn2[5], ia);

#define HH1FC(ra, za, ha, oa)                                                 \
    _Pragma("unroll")                                                         \
    for (int i = 0; i < 6; ++i) {                                             \
      ra = pkfma(hw2[i], sr2[i], ra); za = pkfma(hw2[i], sz2[i], za);         \
      ha = pkfma(hw2[i], sn2[i], ha); oa = pkfma(hw2[i], fw2[i], oa);         \
    }

#define BTAIL(ra, za, ha, ia)                                                 \
    { float ar_ = ra.x + ra.y, az_ = za.x + za.y;                             \
      float hn_ = ha.x + ha.y, an_ = ia.x + ia.y;                             \
      float r_ = sigmoid_s(ar_), zg_ = sigmoid_s(az_);                        \
      float n_ = tanh_s(an_ + r_ * hn_);                                      \
      h2 = n_ + zg_ * (h2 - n_);                                              \
      sq[lane15] = h2;                                                        \
      v4f c0_ = ((const v4f*)sq)[0];                                          \
      v4f c1_ = ((const v4f*)sq)[1];                                          \
      v4f c2_ = ((const v4f*)sq)[2];                                          \
      hw2[0] = vlo(c0_); hw2[1] = vhi(c0_); hw2[2] = vlo(c1_);                \
      hw2[3] = vhi(c1_); hw2[4] = vlo(c2_); hw2[5] = vhi(c2_); }

    for (int k = 0; k < 129; ++k) {
      if (k >= 1) {
        const int par = (k - 1) & 1;
        const int s0 = 4 * (k - 1);
        v4f qa0, qa1, qa2, qb0, qb1, qb2;
        READQ(qa, 0)
        READQ(qb, 1)
        float o0, o1, o2, o3;
        { // S=0: hh1+FC first (hw2 landed a barrier ago) -> covers qa reads
          v2 ra = (v2){br1S, 0.f}, za = (v2){bz1S, 0.f};
          v2 ha = (v2){bh1S, 0.f}, oa = (v2){fb, 0.f};
          HH1FC(ra, za, ha, oa)
          o0 = oa.x + oa.y;
          v2 ia = (v2){bi1S, 0.f};
          IH1(qa, ra, za, ia)
          BTAIL(ra, za, ha, ia)
        }
        READQ(qa, 2)   // prefetch h1 for S=2
        { // S=1: ih1 first -> covers S=0's h2 readback
          v2 ra = (v2){br1S, 0.f}, za = (v2){bz1S, 0.f}, ia = (v2){bi1S, 0.f};
          IH1(qb, ra, za, ia)
          v2 ha = (v2){bh1S, 0.f}, oa = (v2){fb, 0.f};
          HH1FC(ra, za, ha, oa)
          o1 = oa.x + oa.y;
          BTAIL(ra, za, ha, ia)
        }
        READQ(qb, 3)   // prefetch h1 for S=3
        { // S=2
          v2 ra = (v2){br1S, 0.f}, za = (v2){bz1S, 0.f}, ia = (v2){bi1S, 0.f};
          IH1(qa, ra, za, ia)
          v2 ha = (v2){bh1S, 0.f}, oa = (v2){fb, 0.f};
          HH1FC(ra, za, ha, oa)
          o2 = oa.x + oa.y;
          BTAIL(ra, za, ha, ia)
        }
        { // S=3
          v2 ra = (v2){br1S, 0.f}, za = (v2){bz1S, 0.f}, ia = (v2){bi1S, 0.f};
          IH1(qb, ra, za, ia)
          v2 ha = (v2){bh1S, 0.f}, oa = (v2){fb, 0.f};
          HH1FC(ra, za, ha, oa)
          o3 = oa.x + oa.y;
          BTAIL(ra, za, ha, ia)
        }
        if (lane15 == 0) {   // one exec toggle per tick
          if (k >= 2) outp[s0 - 1] = o0;
          outp[s0] = o1; outp[s0 + 1] = o2; outp[s0 + 2] = o3;
        }
      }
      BAR();
    }
#undef READQ
#undef IH1
#undef HH1FC
#undef BTAIL
    // epilogue: FC on h2[Tlen-1]
    v2 oa = (v2){fb, 0.f};
#pragma unroll
    for (int i = 0; i < 6; ++i) oa = pkfma(hw2[i], fw2[i], oa);
    if (lane15 == 0) outp[Tlen - 1] = oa.x + oa.y;
  }
#undef BAR
}

extern "C" void kernel_launch(void* const* d_in, const int* in_sizes, int n_in,
                              void* d_out, int out_size, void* d_ws, size_t ws_size,
                              hipStream_t stream) {
  (void)in_sizes; (void)n_in; (void)d_ws; (void)ws_size; (void)out_size;
  const float* x    = (const float*)d_in[0];
  const float* wih0 = (const float*)d_in[1];
  const float* whh0 = (const float*)d_in[2];
  const float* bih0 = (const float*)d_in[3];
  const float* bhh0 = (const float*)d_in[4];
  const float* wih1 = (const float*)d_in[5];
  const float* whh1 = (const float*)d_in[6];
  const float* bih1 = (const float*)d_in[7];
  const float* bhh1 = (const float*)d_in[8];
  const float* fcw  = (const float*)d_in[9];
  const float* fcb  = (const float*)d_in[10];
  float* out = (float*)d_out;

  hipLaunchKernelGGL(gru2_pipe5, dim3(Bsz / 4), dim3(128), 0, stream,
                     x, wih0, whh0, bih0, bhh0, wih1, whh1, bih1, bhh1, fcw, fcb, out);
}